// Round 13
// baseline (925.512 us; speedup 1.0000x reference)
//
#include <hip/hip_runtime.h>
#include <math.h>

#define BN 16
#define NN 1024
#define DD 384
#define D2 768
#define C2 1536
#define NHEAD 8
#define DH 48

#define SZ_ND   (BN*NN*DD)      /* 6291456  */
#define SZ_N2D  (BN*NN*D2)      /* 12582912 */
#define SZ_NC2  (BN*NN*C2)      /* 25165824 */
#define M2      32768           /* merged rows (2 streams) */
#define MH      16384           /* rows per stream */

typedef __bf16 bf16x8 __attribute__((ext_vector_type(8)));
typedef float f32x4v __attribute__((ext_vector_type(4)));
typedef unsigned short u16x4 __attribute__((ext_vector_type(4)));

__device__ __forceinline__ unsigned short f2bf(float x){
  unsigned int u = __float_as_uint(x);
  u += 0x7FFFu + ((u >> 16) & 1u);          // round-nearest-even to bf16
  return (unsigned short)(u >> 16);
}
__device__ __forceinline__ float bf2f(unsigned short h){
  return __uint_as_float(((unsigned int)h) << 16);
}

// ---------------- block reductions (256 threads = 4 waves) ----------------
__device__ __forceinline__ float blockReduceSum256(float v){
  __shared__ float red[4];
  #pragma unroll
  for (int o=32;o;o>>=1) v += __shfl_down(v,o,64);
  if ((threadIdx.x&63)==0) red[threadIdx.x>>6]=v;
  __syncthreads();
  float r = red[0]+red[1]+red[2]+red[3];
  __syncthreads();
  return r;
}
__device__ __forceinline__ float blockReduceMax256(float v){
  __shared__ float red[4];
  #pragma unroll
  for (int o=32;o;o>>=1) v = fmaxf(v, __shfl_down(v,o,64));
  if ((threadIdx.x&63)==0) red[threadIdx.x>>6]=v;
  __syncthreads();
  float r = fmaxf(fmaxf(red[0],red[1]),fmaxf(red[2],red[3]));
  __syncthreads();
  return r;
}

// ---------------- LayerNorm: one block per row (fp32 out) ----------------
__global__ __launch_bounds__(256) void ln_kernel(const float* __restrict__ in,
    const float* __restrict__ g, const float* __restrict__ b,
    float* __restrict__ out, int C){
  const int row = blockIdx.x;
  const float* x = in + (size_t)row*C;
  float s=0.f;
  for (int i=threadIdx.x;i<C;i+=256) s += x[i];
  s = blockReduceSum256(s);
  const float mu = s / (float)C;
  float v=0.f;
  for (int i=threadIdx.x;i<C;i+=256){ float d = x[i]-mu; v += d*d; }
  v = blockReduceSum256(v);
  const float rs = rsqrtf(v/(float)C + 1e-5f);
  float* o = out + (size_t)row*C;
  for (int i=threadIdx.x;i<C;i+=256) o[i] = (x[i]-mu)*rs*g[i] + b[i];
}

// ---------------- LayerNorm, two-source input, bf16 hi/lo split output ----------
__global__ __launch_bounds__(256) void ln_split2_kernel(const float* __restrict__ in1,
    const float* __restrict__ in2, int Mh,
    const float* __restrict__ g, const float* __restrict__ b,
    unsigned short* __restrict__ oh, unsigned short* __restrict__ ol, int C){
  const int row = blockIdx.x;
  const float* x = (row < Mh) ? (in1 + (size_t)row*C) : (in2 + (size_t)(row-Mh)*C);
  float s=0.f;
  for (int i=threadIdx.x;i<C;i+=256) s += x[i];
  s = blockReduceSum256(s);
  const float mu = s / (float)C;
  float v=0.f;
  for (int i=threadIdx.x;i<C;i+=256){ float d = x[i]-mu; v += d*d; }
  v = blockReduceSum256(v);
  const float rs = rsqrtf(v/(float)C + 1e-5f);
  unsigned short* ohp = oh + (size_t)row*C;
  unsigned short* olp = ol + (size_t)row*C;
  for (int i=threadIdx.x;i<C;i+=256){
    float val = (x[i]-mu)*rs*g[i] + b[i];
    unsigned short hh = f2bf(val);
    ohp[i] = hh; olp[i] = f2bf(val - bf2f(hh));
  }
}

// ---------------- fused phase-B helpers: rowSM(QS) | colSM->KSt | rp_w split | tsplit(n1) ---
// grid = MH + 96 + 1152 + 6144 blocks, branch is block-uniform.
__global__ __launch_bounds__(256) void phaseB_misc_kernel(
    const float* __restrict__ n12,
    unsigned short* __restrict__ QSh, unsigned short* __restrict__ QSl,
    unsigned short* __restrict__ KSt_h, unsigned short* __restrict__ KSt_l,
    unsigned short* __restrict__ n1t_h, unsigned short* __restrict__ n1t_l,
    const float* __restrict__ rpw, unsigned short* __restrict__ rpwh,
    unsigned short* __restrict__ rpwl)
{
  __shared__ float smem[32][33];
  __shared__ float red2[4][64];
  __shared__ float red3[4][64];
  const int bid = blockIdx.x;
  const int t = threadIdx.x;
  if (bid < MH){
    // ---- row softmax over channels on n2 row `bid` -> QS split ----
    const float* x = n12 + (size_t)(MH + bid)*DD;
    float m = -3.0e38f;
    for (int i=t;i<DD;i+=256) m = fmaxf(m, x[i]);
    m = blockReduceMax256(m);
    float s = 0.f;
    for (int i=t;i<DD;i+=256) s += expf(x[i]-m);
    s = blockReduceSum256(s);
    const float inv = 1.f/s;
    unsigned short* ohp = QSh + (size_t)bid*DD;
    unsigned short* olp = QSl + (size_t)bid*DD;
    for (int i=t;i<DD;i+=256){
      float p = expf(x[i]-m)*inv;
      unsigned short hh = f2bf(p);
      ohp[i] = hh; olp[i] = f2bf(p - bf2f(hh));
    }
  } else if (bid < MH + 96){
    // ---- column softmax over tokens, fused transpose-split -> KSt[b][d][n] ----
    const int k = bid - MH;
    const int dblk = k % 6, b = k / 6;
    const int dl = t & 63, nc = t >> 6;
    const int d = dblk*64 + dl;
    const float* p = n12 + (size_t)MH*DD + (size_t)b*NN*DD + d;
    float m = -3.0e38f;
    for (int n=nc*256;n<nc*256+256;n++) m = fmaxf(m, p[(size_t)n*DD]);
    red2[nc][dl] = m; __syncthreads();
    m = fmaxf(fmaxf(red2[0][dl],red2[1][dl]),fmaxf(red2[2][dl],red2[3][dl]));
    float s=0.f;
    for (int n=nc*256;n<nc*256+256;n++) s += expf(p[(size_t)n*DD]-m);
    red3[nc][dl]=s; __syncthreads();
    s = red3[0][dl]+red3[1][dl]+red3[2][dl]+red3[3][dl];
    const float inv = 1.f/s;
    unsigned short* qh = KSt_h + ((size_t)b*DD + d)*NN;
    unsigned short* ql = KSt_l + ((size_t)b*DD + d)*NN;
    for (int n=nc*256;n<nc*256+256;n++){
      float val = expf(p[(size_t)n*DD]-m)*inv;
      unsigned short hh = f2bf(val);
      qh[n] = hh; ql[n] = f2bf(val - bf2f(hh));
    }
  } else if (bid < MH + 96 + 1152){
    // ---- rp_w elementwise split (294912 elements, exact) ----
    const int i = (bid - MH - 96)*256 + t;
    float x = rpw[i];
    unsigned short h = f2bf(x);
    rpwh[i] = h; rpwl[i] = f2bf(x - bf2f(h));
  } else {
    // ---- batched transpose+split of n1: n1t[b][d][n] = n1[b][n][d] ----
    const int k = bid - MH - 96 - 1152;          // [0, 6144)
    const int bx = k % 12;                       // DD/32
    const int by = (k / 12) % 32;                // NN/32
    const int z  = k / 384;                      // BN
    const size_t zb = (size_t)z * NN * DD;
    const float* ip = n12 + zb;                  // n1 half = first MH rows
    unsigned short* ohp = n1t_h + zb;
    unsigned short* olp = n1t_l + zb;
    const int c0 = bx*32, r0 = by*32;
    const int j = t & 31, i4 = t >> 5;
    #pragma unroll
    for (int s=0;s<4;s++){
      int i = i4*4+s;
      smem[i][j] = ip[(size_t)(r0+i)*DD + c0 + j];
    }
    __syncthreads();
    #pragma unroll
    for (int s=0;s<4;s++){
      int i = i4*4+s;
      float x = smem[j][i];
      unsigned short h = f2bf(x);
      ohp[(size_t)(c0+i)*NN + r0 + j] = h;
      olp[(size_t)(c0+i)*NN + r0 + j] = f2bf(x - bf2f(h));
    }
  }
}

// ---------------- channel attention (PACKED u32 qkv input, split bf16 output) -----
__global__ __launch_bounds__(256) void chattn_mfma_kernel(
    const unsigned int* __restrict__ qp, const float* __restrict__ temp,
    unsigned short* __restrict__ coh, unsigned short* __restrict__ col)
{
  const int bh = blockIdx.x, b = bh >> 3, h = bh & 7;
  const int t = threadIdx.x, w = t >> 6, lane = t & 63;
  const int lr = lane & 15, g = lane >> 4;

  __shared__ __align__(16) unsigned char ldsA[27648];
  unsigned short (*Qh)[72] = (unsigned short(*)[72])(ldsA);
  unsigned short (*Ql)[72] = (unsigned short(*)[72])(ldsA + 6912);
  unsigned short (*Kh)[72] = (unsigned short(*)[72])(ldsA + 13824);
  unsigned short (*Kl)[72] = (unsigned short(*)[72])(ldsA + 20736);
  unsigned short (*Vh)[72] = (unsigned short(*)[72])(ldsA);
  unsigned short (*Vl)[72] = (unsigned short(*)[72])(ldsA + 9216);
  __shared__ unsigned short Ph[48][72], Pl[48][72];
  __shared__ float S[48][49];
  __shared__ float qn[48], kn[48];

  const size_t base = (size_t)b*NN*1152 + (size_t)h*48;

  int agrp[3], apr[3], aoff[3];
  #pragma unroll
  for (int l=0;l<3;l++){
    int idx = l*256+t;
    int mo = (idx>=384) ? 1 : 0;
    int a = idx - mo*384;
    agrp[l] = a%12; apr[l] = a/12; aoff[l] = mo*384;
  }

  f32x4v acc[12];
  #pragma unroll
  for (int i=0;i<12;i++) acc[i] = (f32x4v){0.f,0.f,0.f,0.f};

  uint4 p0[3], p1[3];
  #pragma unroll
  for (int l=0;l<3;l++){
    const size_t a = base + (size_t)(apr[l]*2)*1152 + aoff[l] + agrp[l]*4;
    p0[l] = *(const uint4*)(qp + a);
    p1[l] = *(const uint4*)(qp + a + 1152);
  }

  for (int nc=0; nc<16; nc++){
    #pragma unroll
    for (int l=0;l<3;l++){
      unsigned short (*Dh)[72] = aoff[l] ? Kh : Qh;
      unsigned short (*Dl)[72] = aoff[l] ? Kl : Ql;
      const unsigned w0[4] = {p0[l].x, p0[l].y, p0[l].z, p0[l].w};
      const unsigned w1[4] = {p1[l].x, p1[l].y, p1[l].z, p1[l].w};
      #pragma unroll
      for (int c=0;c<4;c++){
        int d = agrp[l]*4+c;
        *(unsigned int*)&Dh[d][apr[l]*2] = (w0[c] & 0xffffu) | (w1[c] << 16);
        *(unsigned int*)&Dl[d][apr[l]*2] = (w0[c] >> 16)     | (w1[c] & 0xffff0000u);
      }
    }
    __syncthreads();
    if (nc < 15){
      #pragma unroll
      for (int l=0;l<3;l++){
        const size_t a = base + (size_t)((nc+1)*64 + apr[l]*2)*1152 + aoff[l] + agrp[l]*4;
        p0[l] = *(const uint4*)(qp + a);
        p1[l] = *(const uint4*)(qp + a + 1152);
      }
    }
    if (w < 3){
      #pragma unroll
      for (int ks=0;ks<2;ks++){
        bf16x8 a_h = *(const bf16x8*)&Qh[w*16+lr][ks*32+g*8];
        bf16x8 a_l = *(const bf16x8*)&Ql[w*16+lr][ks*32+g*8];
        #pragma unroll
        for (int c=0;c<3;c++){
          bf16x8 b_h = *(const bf16x8*)&Kh[c*16+lr][ks*32+g*8];
          bf16x8 b_l = *(const bf16x8*)&Kl[c*16+lr][ks*32+g*8];
          acc[c] = __builtin_amdgcn_mfma_f32_16x16x32_bf16(a_h, b_h, acc[c], 0,0,0);
          acc[c] = __builtin_amdgcn_mfma_f32_16x16x32_bf16(a_l, b_h, acc[c], 0,0,0);
          acc[c] = __builtin_amdgcn_mfma_f32_16x16x32_bf16(a_h, b_l, acc[c], 0,0,0);
        }
      }
    } else {
      #pragma unroll
      for (int ks=0;ks<2;ks++){
        #pragma unroll
        for (int c=0;c<3;c++){
          bf16x8 qh_ = *(const bf16x8*)&Qh[c*16+lr][ks*32+g*8];
          bf16x8 ql_ = *(const bf16x8*)&Ql[c*16+lr][ks*32+g*8];
          bf16x8 kh_ = *(const bf16x8*)&Kh[c*16+lr][ks*32+g*8];
          bf16x8 kl_ = *(const bf16x8*)&Kl[c*16+lr][ks*32+g*8];
          acc[c]   = __builtin_amdgcn_mfma_f32_16x16x32_bf16(qh_, qh_, acc[c],   0,0,0);
          acc[3+c] = __builtin_amdgcn_mfma_f32_16x16x32_bf16(qh_, ql_, acc[3+c], 0,0,0);
          acc[6+c] = __builtin_amdgcn_mfma_f32_16x16x32_bf16(kh_, kh_, acc[6+c], 0,0,0);
          acc[9+c] = __builtin_amdgcn_mfma_f32_16x16x32_bf16(kh_, kl_, acc[9+c], 0,0,0);
        }
      }
    }
    __syncthreads();
  }

  const float tp = temp[h];
  if (w == 3){
    if ((lane>>4) == ((lane&15)>>2)){
      int p = lane & 15, r = p & 3;
      #pragma unroll
      for (int c=0;c<3;c++){
        float q2 = fmaxf(acc[c][r]   + 2.f*acc[3+c][r], 0.f);
        float k2 = fmaxf(acc[6+c][r] + 2.f*acc[9+c][r], 0.f);
        qn[c*16+p] = fmaxf(sqrtf(q2), 1e-12f);
        kn[c*16+p] = fmaxf(sqrtf(k2), 1e-12f);
      }
    }
  }
  __syncthreads();
  if (w < 3){
    #pragma unroll
    for (int c=0;c<3;c++){
      #pragma unroll
      for (int r=0;r<4;r++){
        int i = w*16 + g*4 + r, j = c*16 + lr;
        S[i][j] = acc[c][r]*tp/(qn[i]*kn[j]);
      }
    }
  }
  __syncthreads();

  int vgrp[3], vtk[3];
  #pragma unroll
  for (int l=0;l<3;l++){ int idx=l*256+t; vtk[l]=idx/12; vgrp[l]=idx%12; }
  uint4 pv[3];
  #pragma unroll
  for (int l=0;l<3;l++){
    const size_t a = base + (size_t)vtk[l]*1152 + 768 + vgrp[l]*4;
    pv[l] = *(const uint4*)(qp + a);
  }

  if (t < 48){
    float m = -3.0e38f;
    for (int j=0;j<48;j++) m = fmaxf(m, S[t][j]);
    float s = 0.f;
    for (int j=0;j<48;j++){ float e_ = expf(S[t][j]-m); S[t][j] = e_; s += e_; }
    float inv = 1.f/s;
    for (int j=0;j<48;j++){
      float p = S[t][j]*inv;
      unsigned short hp = f2bf(p);
      Ph[t][j] = hp; Pl[t][j] = f2bf(p - bf2f(hp));
    }
    #pragma unroll
    for (int j=48;j<64;j++){ Ph[t][j]=0; Pl[t][j]=0; }
  } else {
    const u16x4 z4 = (u16x4){0,0,0,0};
    for (int idx=t-48; idx<512; idx+=208){
      int tk = idx>>3, q = idx&7;
      if (q<4) *(u16x4*)&Vh[tk][48+(q&3)*4] = z4;
      else     *(u16x4*)&Vl[tk][48+(q&3)*4] = z4;
    }
  }
  __syncthreads();

  bf16x8 pfh[3][2], pfl[3][2];
  #pragma unroll
  for (int it=0;it<3;it++)
    #pragma unroll
    for (int ks=0;ks<2;ks++){
      pfh[it][ks] = *(const bf16x8*)&Ph[it*16+lr][ks*32+g*8];
      pfl[it][ks] = *(const bf16x8*)&Pl[it*16+lr][ks*32+g*8];
    }

  for (int vc=0; vc<16; vc++){
    #pragma unroll
    for (int l=0;l<3;l++){
      const unsigned pw[4] = {pv[l].x, pv[l].y, pv[l].z, pv[l].w};
      u16x4 hv, lv;
      #pragma unroll
      for (int c=0;c<4;c++){
        hv[c] = (unsigned short)(pw[c] & 0xffffu);
        lv[c] = (unsigned short)(pw[c] >> 16);
      }
      *(u16x4*)&Vh[vtk[l]][vgrp[l]*4] = hv;
      *(u16x4*)&Vl[vtk[l]][vgrp[l]*4] = lv;
    }
    __syncthreads();
    if (vc < 15){
      #pragma unroll
      for (int l=0;l<3;l++){
        const size_t a = base + (size_t)((vc+1)*64+vtk[l])*1152 + 768 + vgrp[l]*4;
        pv[l] = *(const uint4*)(qp + a);
      }
    }
    bf16x8 vfh[2], vfl[2];
    #pragma unroll
    for (int ks=0;ks<2;ks++){
      vfh[ks] = *(const bf16x8*)&Vh[w*16+lr][ks*32+g*8];
      vfl[ks] = *(const bf16x8*)&Vl[w*16+lr][ks*32+g*8];
    }
    f32x4v o[3];
    #pragma unroll
    for (int it=0;it<3;it++) o[it] = (f32x4v){0.f,0.f,0.f,0.f};
    #pragma unroll
    for (int it=0;it<3;it++)
      #pragma unroll
      for (int ks=0;ks<2;ks++){
        o[it] = __builtin_amdgcn_mfma_f32_16x16x32_bf16(pfh[it][ks], vfh[ks], o[it], 0,0,0);
        o[it] = __builtin_amdgcn_mfma_f32_16x16x32_bf16(pfl[it][ks], vfh[ks], o[it], 0,0,0);
        o[it] = __builtin_amdgcn_mfma_f32_16x16x32_bf16(pfh[it][ks], vfl[ks], o[it], 0,0,0);
      }
    const int n = vc*64 + w*16 + lr;
    #pragma unroll
    for (int it=0;it<3;it++){
      const size_t off = ((size_t)b*NN + n)*DD + h*48 + it*16 + g*4;
      u16x4 hv, lv;
      #pragma unroll
      for (int r=0;r<4;r++){
        float x = o[it][r];
        unsigned short hh = f2bf(x);
        hv[r] = hh; lv[r] = f2bf(x - bf2f(hh));
      }
      *(u16x4*)(coh + off) = hv;
      *(u16x4*)(col + off) = lv;
    }
    __syncthreads();
  }
}

// ---------------- fused phase-A weight prep: qkv (432 blocks) + proj (144) -------
__global__ __launch_bounds__(256) void wprep2_kernel(
    const float* __restrict__ qkvw, unsigned short* __restrict__ qwh, unsigned short* __restrict__ qwl,
    const float* __restrict__ projw, unsigned short* __restrict__ pwh, unsigned short* __restrict__ pwl)
{
  __shared__ float tile[32][33];
  const int bid = blockIdx.x;
  const float* in; unsigned short *oh, *ol; int Nin, bx, by;
  if (bid < 432){ in = qkvw;  oh = qwh; ol = qwl; Nin = 1152; bx = bid % 36; by = bid / 36; }
  else { int k = bid - 432; in = projw; oh = pwh; ol = pwl; Nin = DD;   bx = k % 12;  by = k / 12; }
  const int n0 = bx*32, k0 = by*32;
  const int j = threadIdx.x & 31, i4 = threadIdx.x >> 5;
  #pragma unroll
  for (int s=0;s<4;s++){
    int i = i4*4+s;
    tile[i][j] = in[(size_t)(k0+i)*Nin + n0 + j];
  }
  __syncthreads();
  #pragma unroll
  for (int s=0;s<4;s++){
    int i = i4*4+s;
    float x = tile[j][i];
    unsigned short h = f2bf(x);
    oh[(size_t)(n0+i)*DD + k0 + j] = h;
    ol[(size_t)(n0+i)*DD + k0 + j] = f2bf(x - bf2f(h));
  }
}

// ---------------- weight prep: transpose [K,Nin] -> bf16 hi/lo (fc1/fc2) ---------
__global__ __launch_bounds__(256) void wconv_t_kernel(const float* __restrict__ in,
    unsigned short* __restrict__ oh, unsigned short* __restrict__ ol, int K, int Nin){
  __shared__ float tile[32][33];
  const int n0 = blockIdx.x*32, k0 = blockIdx.y*32;
  const int j = threadIdx.x & 31, i4 = threadIdx.x >> 5;
  #pragma unroll
  for (int s=0;s<4;s++){
    int i = i4*4+s;
    tile[i][j] = (n0 + j < Nin) ? in[(size_t)(k0+i)*Nin + n0 + j] : 0.f;
  }
  __syncthreads();
  #pragma unroll
  for (int s=0;s<4;s++){
    int i = i4*4+s;
    float x = tile[j][i];
    unsigned short h = f2bf(x);
    oh[(size_t)(n0+i)*K + k0 + j] = h;
    ol[(size_t)(n0+i)*K + k0 + j] = f2bf(x - bf2f(h));
  }
}

// ---------------- bf16x3 MFMA GEMM 128x128: dbuf LDS + distance-2 prefetch --------
// Verified structure (R6..R12): 2 blocks/CU, 0 bank conflicts, ~830-860 TF eff.
template<bool BIAS_, bool RES_, bool SPLIT_, bool PACK32_>
__global__ __launch_bounds__(256) void gemm_bf16x3s_kernel(
    const unsigned short* __restrict__ Ah, const unsigned short* __restrict__ Al,
    const unsigned short* __restrict__ Bh, const unsigned short* __restrict__ Bl,
    const float* __restrict__ bias, const float* __restrict__ res,
    const float* __restrict__ res2, int Mh2,
    float* __restrict__ C, unsigned short* __restrict__ Ch, unsigned short* __restrict__ Cl,
    int M, int N, int K, size_t sAz, size_t sBz, size_t sCz)
{
  const int t = threadIdx.x;
  const int nwg = gridDim.x*gridDim.y;
  const int lin = blockIdx.y*gridDim.x + blockIdx.x;
  const int swz = ((nwg & 7)==0) ? ((lin & 7)*(nwg >> 3) + (lin >> 3)) : lin;
  const int bx = swz % gridDim.x, by = swz / gridDim.x;
  const int m0 = by*128, n0 = bx*128;
  const size_t zo = (size_t)blockIdx.z;

  __shared__ unsigned short As_h0[128][32], As_l0[128][32];
  __shared__ unsigned short Bs_h0[128][32], Bs_l0[128][32];
  __shared__ unsigned short As_h1[128][32], As_l1[128][32];
  __shared__ unsigned short Bs_h1[128][32], Bs_l1[128][32];

  const unsigned short* Ahb = Ah + zo*sAz + (size_t)m0*K;
  const unsigned short* Alb = Al + zo*sAz + (size_t)m0*K;
  const unsigned short* Bhb = Bh + zo*sBz + (size_t)n0*K;
  const unsigned short* Blb = Bl + zo*sBz + (size_t)n0*K;

  f32x4v acc[4][4];
  #pragma unroll
  for (int i=0;i<4;i++)
    #pragma unroll
    for (int j=0;j<4;j++) acc[i][j] = (f32x4v){0.f,0.f,0.f,0.f};

  const int w  = t >> 6;
  const int wm = w >> 1, wn = w & 1;
  const int lr = t & 15, g = (t & 63) >> 4;
  const int srow = t >> 1;
  const int kb0  = (t & 1)*2;
  const int ssw  = (srow >> 1) & 3;
  const int ks0  = ((kb0+0) ^ ssw)*8;
  const int ks1  = ((kb0+1) ^ ssw)*8;

  uint4 aAh0,aAh1,aAl0,aAl1,aBh0,aBh1,aBl0,aBl1;
  uint4 bAh0,bAh1,bAl0,bAl1,bBh0,bBh1,bBl0,bBl1;

#define LOADT(P, K0) { \
    const size_t go0 = (size_t)srow*K + (size_t)(K0) + (size_t)(kb0*8); \
    P##Ah0 = *(const uint4*)(Ahb + go0); P##Ah1 = *(const uint4*)(Ahb + go0 + 8); \
    P##Al0 = *(const uint4*)(Alb + go0); P##Al1 = *(const uint4*)(Alb + go0 + 8); \
    P##Bh0 = *(const uint4*)(Bhb + go0); P##Bh1 = *(const uint4*)(Bhb + go0 + 8); \
    P##Bl0 = *(const uint4*)(Blb + go0); P##Bl1 = *(const uint4*)(Blb + go0 + 8); }

#define WRITET(BUF, P) { \
    *(uint4*)&As_h##BUF[srow][ks0] = P##Ah0; *(uint4*)&As_h##BUF[srow][ks1] = P##Ah1; \
    *(uint4*)&As_l##BUF[srow][ks0] = P##Al0; *(uint4*)&As_l##BUF[srow][ks1] = P##Al1; \
    *(uint4*)&Bs_h##BUF[srow][ks0] = P##Bh0; *(uint4*)&Bs_h##BUF[srow][ks1] = P##Bh1; \
    *(uint4*)&Bs_l##BUF[srow][ks0] = P##Bl0; *(uint4*)&Bs_l##BUF[srow][ks1] = P##Bl1; }

#define COMPUTET(BUF) { \
    bf16x8 ah[4], al[4], bhf[4], blf[4]; \
    _Pragma("unroll") \
    for (int i=0;i<4;i++){ \
      const int ra = wm*64 + i*16 + lr; \
      const int ka = (g ^ ((ra>>1)&3))*8; \
      ah[i]  = *(const bf16x8*)&As_h##BUF[ra][ka]; \
      al[i]  = *(const bf16x8*)&As_l##BUF[ra][ka]; \
      const int rb = wn*64 + i*16 + lr; \
      const int kb = (g ^ ((rb>>1)&3))*8; \
      bhf[i] = *(const bf16x8*)&Bs_h##BUF[rb][kb]; \
      blf[i] = *(const bf16x8*)&Bs_l##BUF[rb][kb]; \
    } \
    _Pragma("unroll") \
    for (int mi=0;mi<4;mi++) \
      _Pragma("unroll") \
      for (int ni=0;ni<4;ni++){ \
        f32x4v c_ = acc[mi][ni]; \
        c_ = __builtin_amdgcn_mfma_f32_16x16x32_bf16(ah[mi], bhf[ni], c_, 0,0,0); \
        c_ = __builtin_amdgcn_mfma_f32_16x16x32_bf16(al[mi], bhf[ni], c_, 0,0,0); \
        c_ = __builtin_amdgcn_mfma_f32_16x16x32_bf16(ah[mi], blf[ni], c_, 0,0,0); \
        acc[mi][ni] = c_; \
      } }

  const int nk = K >> 5;
  LOADT(a, 0);
  WRITET(0, a);
  LOADT(a, 32);
  __syncthreads();

  for (int kt = 0; kt < nk; kt += 2){
    if (kt+2 < nk) LOADT(b, (kt+2)*32);
    COMPUTET(0);
    WRITET(1, a);
    __syncthreads();
    if (kt+3 < nk) LOADT(a, (kt+3)*32);
    COMPUTET(1);
    if (kt+2 < nk){ WRITET(0, b); }
    __syncthreads();
  }

#undef LOADT
#undef WRITET
#undef COMPUTET

  if (PACK32_){
    unsigned int* Cp = (unsigned int*)Ch + zo*sCz;
    #pragma unroll
    for (int ni=0;ni<4;ni++){
      const int col = n0 + wn*64 + ni*16 + lr;
      #pragma unroll
      for (int mi=0;mi<4;mi++){
        const int r0 = m0 + wm*64 + mi*16 + g*4;
        #pragma unroll
        for (int r=0;r<4;r++){
          float v = acc[mi][ni][r];
          unsigned short hv = f2bf(v);
          unsigned short lv = f2bf(v - bf2f(hv));
          Cp[(size_t)(r0+r)*N + col] = (unsigned)hv | ((unsigned)lv << 16);
        }
      }
    }
  } else if (SPLIT_){
    unsigned short* Chb = Ch + zo*sCz;
    unsigned short* Clb = Cl + zo*sCz;
    #pragma unroll
    for (int ni=0;ni<4;ni++){
      const int col = n0 + wn*64 + ni*16 + lr;
      #pragma unroll
      for (int mi=0;mi<4;mi++){
        const int r0 = m0 + wm*64 + mi*16 + g*4;
        #pragma unroll
        for (int r=0;r<4;r++){
          float v = acc[mi][ni][r];
          unsigned short hv = f2bf(v);
          const size_t off = (size_t)(r0+r)*N + col;
          Chb[off] = hv;
          Clb[off] = f2bf(v - bf2f(hv));
        }
      }
    }
  } else {
    float* Cb = C + zo*sCz;
    const float* resb = nullptr;
    size_t roff = 0;
    if (RES_){
      if (res2 != nullptr && m0 >= Mh2){ resb = res2; roff = (size_t)Mh2; }
      else resb = res + zo*sCz;
    }
    #pragma unroll
    for (int ni=0;ni<4;ni++){
      const int col = n0 + wn*64 + ni*16 + lr;
      const float bb = BIAS_ ? bias[col] : 0.f;
      #pragma unroll
      for (int mi=0;mi<4;mi++){
        const int r0 = m0 + wm*64 + mi*16 + g*4;
        #pragma unroll
        for (int r=0;r<4;r++){
          float v = acc[mi][ni][r] + bb;
          if (RES_) v += resb[((size_t)(r0+r) - roff)*N + col];
          Cb[(size_t)(r0+r)*N + col] = v;
        }
      }
    }
  }
}

// ---------------- LN(rep)+concat -> tx, fused LN2 -> split y2 ----------------
__global__ __launch_bounds__(256) void ln_concat_ln2_kernel(const float* __restrict__ rep,
    const float* __restrict__ g1, const float* __restrict__ b1,
    const float* __restrict__ ch1, const float* __restrict__ ch2,
    const float* __restrict__ g2, const float* __restrict__ b2,
    float* __restrict__ tx, unsigned short* __restrict__ y2h, unsigned short* __restrict__ y2l){
  const int row = blockIdx.x;
  const float* x = rep + (size_t)row*D2;
  float xv[3];
  float s=0.f;
  #pragma unroll
  for (int q=0;q<3;q++){ xv[q] = x[threadIdx.x + q*256]; s += xv[q]; }
  s = blockReduceSum256(s);
  const float mu = s / (float)D2;
  float v=0.f;
  #pragma unroll
  for (int q=0;q<3;q++){ float d = xv[q]-mu; v += d*d; }
  v = blockReduceSum256(v);
  const float rs = rsqrtf(v/(float)D2 + 1e-5f);
  float tv[3];
  #pragma unroll
  for (int q=0;q<3;q++){
    int i = threadIdx.x + q*256;
    float val = (xv[q]-mu)*rs*g1[i] + b1[i];
    float rv = (i<DD) ? ch1[(size_t)row*DD + i] : ch2[(size_t)row*DD + i - DD];
    tv[q] = val + rv;
    tx[(size_t)row*D2 + i] = tv[q];
  }
  float s2 = tv[0]+tv[1]+tv[2];
  s2 = blockReduceSum256(s2);
  const float mu2 = s2 / (float)D2;
  float v2=0.f;
  #pragma unroll
  for (int q=0;q<3;q++){ float d = tv[q]-mu2; v2 += d*d; }
  v2 = blockReduceSum256(v2);
  const float rs2 = rsqrtf(v2/(float)D2 + 1e-5f);
  #pragma unroll
  for (int q=0;q<3;q++){
    int i = threadIdx.x + q*256;
    float y = (tv[q]-mu2)*rs2*g2[i] + b2[i];
    unsigned short hh = f2bf(y);
    y2h[(size_t)row*D2 + i] = hh;
    y2l[(size_t)row*D2 + i] = f2bf(y - bf2f(hh));
  }
}

// ---------------- depthwise 3x3 conv + bias + exact GELU (split bf16 out) --------
__global__ __launch_bounds__(256) void dwconv_gelu_kernel(const float* __restrict__ h1,
    const float* __restrict__ w, const float* __restrict__ bias,
    unsigned short* __restrict__ gh, unsigned short* __restrict__ gl){
  const int idx = blockIdx.x*256 + threadIdx.x;
  const int b   = idx / 12288;
  const int r   = idx - b*12288;
  const int hh  = r / 384;
  const int c4  = r - hh*384;
  const int c   = c4*4;
  const float* base = h1 + (size_t)b*NN*C2 + c;
  const size_t obase = ((size_t)b*NN + hh*32)*C2 + c;

  f32x4v wk[9];
  #pragma unroll
  for (int k=0;k<9;k++){
    f32x4v t_;
    #pragma unroll
    for (int q=0;q<4;q++) t_[q] = w[(size_t)(c+q)*9 + k];
    wk[k] = t_;
  }
  f32x4v bvv;
  {
    const float4 bb = *(const float4*)(bias + c);
    bvv = (f32x4v){bb.x, bb.y, bb.z, bb.w};
  }

  const bool hm = (hh > 0), hp = (hh < 31);
  const f32x4v z4 = (f32x4v){0.f,0.f,0.f,0.f};
  const size_t rm = (size_t)((hh-1)*32)*C2;
  const size_t r0 = (size_t)( hh   *32)*C2;
  const size_t rp = (size_t)((hh+1)*32)*C2;

  f32x4v A0,A1,A2, B0,B1,B2, C0,C1,C2c;
  A0=z4; A1=z4; A2=z4;
  B0 = hm ? *(const f32x4v*)(base + rm) : z4;
  B1 =      *(const f32x4v*)(base + r0);
  B2 = hp ? *(const f32x4v*)(base + rp) : z4;
  C0 = hm ? *(const f32x4v*)(base + rm + C2) : z4;
  C1 =      *(const f32x4v*)(base + r0 + C2);
  C2c= hp ? *(const f32x4v*)(base + rp + C2) : z4;

  for (int ww=0; ww<32; ww++){
    f32x4v N0,N1,N2;
    if (ww < 30){
      const size_t co_ = (size_t)(ww+2)*C2;
      N0 = hm ? *(const f32x4v*)(base + rm + co_) : z4;
      N1 =      *(const f32x4v*)(base + r0 + co_) ;
      N2 = hp ? *(const f32x4v*)(base + rp + co_) : z4;
    } else { N0=z4; N1=z4; N2=z4; }

    f32x4v s = bvv;
    s += wk[0]*A0 + wk[1]*B0 + wk[2]*C0;
    s += wk[3]*A1 + wk[4]*B1 + wk[5]*C1;
    s += wk[6]*A2 + wk[7]*B2 + wk[8]*C2c;

    u16x4 hv, lv;
    #pragma unroll
    for (int q=0;q<4;q++){
      float rlt = 0.5f*s[q]*(1.f + erff(s[q]*0.70710678118654752f));
      unsigned short hhv = f2bf(rlt);
      hv[q] = hhv; lv[q] = f2bf(rlt - bf2f(hhv));
    }
    *(u16x4*)(gh + obase + (size_t)ww*C2) = hv;
    *(u16x4*)(gl + obase + (size_t)ww*C2) = lv;

    A0=B0; A1=B1; A2=B2;
    B0=C0; B1=C1; B2=C2c;
    C0=N0; C1=N1; C2c=N2;
  }
}

// ---------------- launch ----------------
extern "C" void kernel_launch(void* const* d_in, const int* in_sizes, int n_in,
                              void* d_out, int out_size, void* d_ws, size_t ws_size,
                              hipStream_t stream) {
  const float* x1     = (const float*)d_in[0];
  const float* x2     = (const float*)d_in[1];
  const float* ln1_g  = (const float*)d_in[2];
  const float* ln1_b  = (const float*)d_in[3];
  const float* qkv_w  = (const float*)d_in[4];
  const float* ca_temp= (const float*)d_in[5];
  const float* proj_w = (const float*)d_in[6];
  const float* proj_b = (const float*)d_in[7];
  const float* ln3_g  = (const float*)d_in[8];
  const float* ln3_b  = (const float*)d_in[9];
  const float* rp_w   = (const float*)d_in[10];
  const float* rp_b   = (const float*)d_in[11];
  const float* cn_g   = (const float*)d_in[12];
  const float* cn_b   = (const float*)d_in[13];
  const float* ln2_g  = (const float*)d_in[14];
  const float* ln2_b  = (const float*)d_in[15];
  const float* fc1_w  = (const float*)d_in[16];
  const float* fc1_b  = (const float*)d_in[17];
  const float* dw_w   = (const float*)d_in[18];
  const float* dw_b   = (const float*)d_in[19];
  const float* fc2_w  = (const float*)d_in[20];
  const float* fc2_b  = (const float*)d_in[21];
  float* out = (float*)d_out;
  float* W   = (float*)d_ws;

  // ---- workspace plan (identical to R11/R12) ----
  unsigned short* ycoh = (unsigned short*)out;
  unsigned short* ycol = ycoh + 12582912u;
  unsigned short* coh  = ycoh;
  unsigned short* col  = ycol;
  unsigned int*   qkvp = (unsigned int*)W;                 // 32768*1152 u32
  unsigned short* qkvwT_h  = (unsigned short*)(W + 37748736ull);
  unsigned short* qkvwT_l  = qkvwT_h + 442368u;
  unsigned short* projwT_h = qkvwT_l + 442368u;
  unsigned short* projwT_l = projwT_h + 147456u;
  float* ch12 = W;
  float* n12  = W + 12582912ull;
  unsigned short* QSh = (unsigned short*)(W + 25165824ull);
  unsigned short* QSl = QSh + 6291456u;
  unsigned short* KSt_h = (unsigned short*)(W + 31457280ull);
  unsigned short* KSt_l = KSt_h + 6291456u;
  unsigned short* rpw_h = (unsigned short*)(W + 37748736ull);
  unsigned short* rpw_l = rpw_h + 294912u;
  unsigned short* n1t_h = (unsigned short*)(W + 38043648ull);
  unsigned short* n1t_l = n1t_h + 6291456u;
  unsigned short* ctxT_h = (unsigned short*)(W + 12582912ull);
  unsigned short* ctxT_l = ctxT_h + 2359296u;
  unsigned short* ATbh = (unsigned short*)(W + 14942208ull);
  unsigned short* ATbl = ATbh + 6291456u;
  float* rep = W + 25165824ull;
  float* txp = out;
  unsigned short* y2h = (unsigned short*)(W + 37748736ull);
  unsigned short* y2l = y2h + 12582912u;
  float* h1 = W;
  unsigned short* fc1wT_h = (unsigned short*)(W + 25165824ull);
  unsigned short* fc1wT_l = fc1wT_h + 1179648u;
  unsigned short* gh = (unsigned short*)(W + 25165824ull);
  unsigned short* gl = (unsigned short*)(W + 37748736ull);
  unsigned short* fc2wT_h = (unsigned short*)W;
  unsigned short* fc2wT_l = fc2wT_h + 1179648u;

  // ---- phase-A weight prep (qkv + proj fused, 576 blocks) ----
  wprep2_kernel<<<dim3(576), dim3(256), 0, stream>>>(
      qkv_w, qkvwT_h, qkvwT_l, proj_w, projwT_h, projwT_l);

  // ---- channel attention, merged streams (batch 32) ----
  ln_split2_kernel<<<dim3(M2), dim3(256), 0, stream>>>(x1, x2, MH, ln1_g, ln1_b, ycoh, ycol, DD);
  gemm_bf16x3s_kernel<false,false,false,true><<<dim3(1152/128, M2/128), dim3(256), 0, stream>>>(
      ycoh, ycol, qkvwT_h, qkvwT_l, nullptr, nullptr, nullptr, 0,
      nullptr, (unsigned short*)qkvp, nullptr, M2, 1152, DD, 0,0,0);
  chattn_mfma_kernel<<<dim3(32*NHEAD), dim3(256), 0, stream>>>(qkvp, ca_temp, coh, col);
  gemm_bf16x3s_kernel<true,true,false,false><<<dim3(DD/128, M2/128), dim3(256), 0, stream>>>(
      coh, col, projwT_h, projwT_l, proj_b, x1, x2, MH,
      ch12, nullptr, nullptr, M2, DD, DD, 0,0,0);

  // ---- cross attention ----
  ln_kernel<<<dim3(M2), dim3(256), 0, stream>>>(ch12, ln3_g, ln3_b, n12, DD);
  // fused: rowSM(QS) | colSM->KSt | rp_w split | tsplit(n1)
  phaseB_misc_kernel<<<dim3(MH + 96 + 1152 + 6144), dim3(256), 0, stream>>>(
      n12, QSh, QSl, KSt_h, KSt_l, n1t_h, n1t_l, rp_w, rpw_h, rpw_l);
  // ctxT[b][d][e] = sum_n n1[n][d]*KS[n][e]
  gemm_bf16x3s_kernel<false,false,true,false><<<dim3(DD/128, DD/128, BN), dim3(256), 0, stream>>>(
      n1t_h, n1t_l, KSt_h, KSt_l, nullptr, nullptr, nullptr, 0,
      nullptr, ctxT_h, ctxT_l, DD, DD, NN, (size_t)DD*NN, (size_t)DD*NN, (size_t)DD*DD);
  // ATb[b][n][d] = sum_e QS[n][e]*ctxT[d][e]
  gemm_bf16x3s_kernel<false,false,true,false><<<dim3(DD/128, NN/128, BN), dim3(256), 0, stream>>>(
      QSh, QSl, ctxT_h, ctxT_l, nullptr, nullptr, nullptr, 0,
      nullptr, ATbh, ATbl, NN, DD, DD, (size_t)NN*DD, (size_t)DD*DD, (size_t)NN*DD);
  // rep = ATb [MH,D] * rp_w^T + rp_b
  gemm_bf16x3s_kernel<true,false,false,false><<<dim3(D2/128, MH/128), dim3(256), 0, stream>>>(
      ATbh, ATbl, rpw_h, rpw_l, rp_b, nullptr, nullptr, 0,
      rep, nullptr, nullptr, MH, D2, DD, 0,0,0);
  // tx = concat(ch1,ch2) + LN(rep); fused LN2 -> split y2
  ln_concat_ln2_kernel<<<dim3(MH), dim3(256), 0, stream>>>(
      rep, cn_g, cn_b, ch12, ch12 + (size_t)MH*DD, ln2_g, ln2_b, txp, y2h, y2l);

  // ---- mix FFN ----
  wconv_t_kernel<<<dim3(C2/32, D2/32), dim3(256), 0, stream>>>(fc1_w, fc1wT_h, fc1wT_l, D2, C2);
  gemm_bf16x3s_kernel<true,false,false,false><<<dim3(C2/128, MH/128), dim3(256), 0, stream>>>(
      y2h, y2l, fc1wT_h, fc1wT_l, fc1_b, nullptr, nullptr, 0,
      h1, nullptr, nullptr, MH, C2, D2, 0,0,0);
  dwconv_gelu_kernel<<<dim3(196608/256), dim3(256), 0, stream>>>(h1, dw_w, dw_b, gh, gl);
  wconv_t_kernel<<<dim3(D2/32, C2/32), dim3(256), 0, stream>>>(fc2_w, fc2wT_h, fc2wT_l, C2, D2);
  gemm_bf16x3s_kernel<true,true,false,false><<<dim3(D2/128, MH/128), dim3(256), 0, stream>>>(
      gh, gl, fc2wT_h, fc2wT_l, fc2_b, txp, nullptr, 0,
      out, nullptr, nullptr, MH, D2, C2, 0,0,0);
}

// Round 14
// 842.883 us; speedup vs baseline: 1.0980x; 1.0980x over previous
//
#include <hip/hip_runtime.h>
#include <math.h>

#define BN 16
#define NN 1024
#define DD 384
#define D2 768
#define C2 1536
#define NHEAD 8
#define DH 48

#define SZ_ND   (BN*NN*DD)      /* 6291456  */
#define SZ_N2D  (BN*NN*D2)      /* 12582912 */
#define SZ_NC2  (BN*NN*C2)      /* 25165824 */
#define M2      32768           /* merged rows (2 streams) */
#define MH      16384           /* rows per stream */

typedef __bf16 bf16x8 __attribute__((ext_vector_type(8)));
typedef float f32x4v __attribute__((ext_vector_type(4)));
typedef unsigned short u16x4 __attribute__((ext_vector_type(4)));

__device__ __forceinline__ unsigned short f2bf(float x){
  unsigned int u = __float_as_uint(x);
  u += 0x7FFFu + ((u >> 16) & 1u);          // round-nearest-even to bf16
  return (unsigned short)(u >> 16);
}
__device__ __forceinline__ float bf2f(unsigned short h){
  return __uint_as_float(((unsigned int)h) << 16);
}

// ---------------- block reductions (256 threads = 4 waves) ----------------
__device__ __forceinline__ float blockReduceSum256(float v){
  __shared__ float red[4];
  #pragma unroll
  for (int o=32;o;o>>=1) v += __shfl_down(v,o,64);
  if ((threadIdx.x&63)==0) red[threadIdx.x>>6]=v;
  __syncthreads();
  float r = red[0]+red[1]+red[2]+red[3];
  __syncthreads();
  return r;
}
__device__ __forceinline__ float blockReduceMax256(float v){
  __shared__ float red[4];
  #pragma unroll
  for (int o=32;o;o>>=1) v = fmaxf(v, __shfl_down(v,o,64));
  if ((threadIdx.x&63)==0) red[threadIdx.x>>6]=v;
  __syncthreads();
  float r = fmaxf(fmaxf(red[0],red[1]),fmaxf(red[2],red[3]));
  __syncthreads();
  return r;
}

// ---------------- LayerNorm: one block per row (fp32 out) ----------------
__global__ __launch_bounds__(256) void ln_kernel(const float* __restrict__ in,
    const float* __restrict__ g, const float* __restrict__ b,
    float* __restrict__ out, int C){
  const int row = blockIdx.x;
  const float* x = in + (size_t)row*C;
  float s=0.f;
  for (int i=threadIdx.x;i<C;i+=256) s += x[i];
  s = blockReduceSum256(s);
  const float mu = s / (float)C;
  float v=0.f;
  for (int i=threadIdx.x;i<C;i+=256){ float d = x[i]-mu; v += d*d; }
  v = blockReduceSum256(v);
  const float rs = rsqrtf(v/(float)C + 1e-5f);
  float* o = out + (size_t)row*C;
  for (int i=threadIdx.x;i<C;i+=256) o[i] = (x[i]-mu)*rs*g[i] + b[i];
}

// ---------------- LayerNorm, two-source input, bf16 hi/lo split output ----------
__global__ __launch_bounds__(256) void ln_split2_kernel(const float* __restrict__ in1,
    const float* __restrict__ in2, int Mh,
    const float* __restrict__ g, const float* __restrict__ b,
    unsigned short* __restrict__ oh, unsigned short* __restrict__ ol, int C){
  const int row = blockIdx.x;
  const float* x = (row < Mh) ? (in1 + (size_t)row*C) : (in2 + (size_t)(row-Mh)*C);
  float s=0.f;
  for (int i=threadIdx.x;i<C;i+=256) s += x[i];
  s = blockReduceSum256(s);
  const float mu = s / (float)C;
  float v=0.f;
  for (int i=threadIdx.x;i<C;i+=256){ float d = x[i]-mu; v += d*d; }
  v = blockReduceSum256(v);
  const float rs = rsqrtf(v/(float)C + 1e-5f);
  unsigned short* ohp = oh + (size_t)row*C;
  unsigned short* olp = ol + (size_t)row*C;
  for (int i=threadIdx.x;i<C;i+=256){
    float val = (x[i]-mu)*rs*g[i] + b[i];
    unsigned short hh = f2bf(val);
    ohp[i] = hh; olp[i] = f2bf(val - bf2f(hh));
  }
}

// ---------------- row softmax with bf16 hi/lo split output (QS) ----------------
__global__ __launch_bounds__(256) void rowsoftmax_split_kernel(const float* __restrict__ in,
    unsigned short* __restrict__ oh, unsigned short* __restrict__ ol, int C){
  const int row = blockIdx.x;
  const float* x = in + (size_t)row*C;
  float m = -3.0e38f;
  for (int i=threadIdx.x;i<C;i+=256) m = fmaxf(m, x[i]);
  m = blockReduceMax256(m);
  float s = 0.f;
  for (int i=threadIdx.x;i<C;i+=256) s += expf(x[i]-m);
  s = blockReduceSum256(s);
  const float inv = 1.f/s;
  unsigned short* ohp = oh + (size_t)row*C;
  unsigned short* olp = ol + (size_t)row*C;
  for (int i=threadIdx.x;i<C;i+=256){
    float p = expf(x[i]-m)*inv;
    unsigned short hh = f2bf(p);
    ohp[i] = hh; olp[i] = f2bf(p - bf2f(hh));
  }
}

// ---------------- column softmax over tokens n: tiled, coalesced, online ---------
// grid (DD/32, BN), 256 threads. Owns a 32-d stripe; 16 tiles of 64n x 32d are
// loaded coalesced into LDS (transpose), online max/sum (2 data passes total),
// outputs [b][d][n] split planes written via LDS transpose (128B coalesced).
__global__ __launch_bounds__(256) void colsoftmax_tsplit_kernel(const float* __restrict__ in,
    unsigned short* __restrict__ oh, unsigned short* __restrict__ ol){
  __shared__ float tile[64][33];
  __shared__ unsigned short outh[32][66], outl[32][66];
  __shared__ float redm[8][32], reds[8][32];
  const int d0 = blockIdx.x*32, b = blockIdx.y;
  const int t = threadIdx.x, dl = t & 31, nc = t >> 5;   // nc in [0,8)
  const float* p = in + (size_t)b*NN*DD + d0;

  float m_run = -3.0e38f, s_run = 0.f;
  for (int tb = 0; tb < 16; tb++){
    const int n0 = tb*64;
    #pragma unroll
    for (int k=0;k<8;k++){
      int e = t + k*256;
      int row = e >> 5, col = e & 31;
      tile[row][col] = p[(size_t)(n0+row)*DD + col];
    }
    __syncthreads();
    float lm = -3.0e38f;
    #pragma unroll
    for (int r=0;r<8;r++) lm = fmaxf(lm, tile[nc*8+r][dl]);
    redm[nc][dl] = lm;
    __syncthreads();
    float tm = redm[0][dl];
    #pragma unroll
    for (int q=1;q<8;q++) tm = fmaxf(tm, redm[q][dl]);
    float m_new = fmaxf(m_run, tm);
    float ls = 0.f;
    #pragma unroll
    for (int r=0;r<8;r++) ls += expf(tile[nc*8+r][dl] - m_new);
    reds[nc][dl] = ls;
    __syncthreads();
    float ts = reds[0][dl];
    #pragma unroll
    for (int q=1;q<8;q++) ts += reds[q][dl];
    s_run = s_run * expf(m_run - m_new) + ts;
    m_run = m_new;
    __syncthreads();
  }

  const float inv = 1.f / s_run, mm = m_run;
  unsigned short* qh = oh + ((size_t)b*DD + d0)*NN;
  unsigned short* ql = ol + ((size_t)b*DD + d0)*NN;
  for (int tb = 0; tb < 16; tb++){
    const int n0 = tb*64;
    #pragma unroll
    for (int k=0;k<8;k++){
      int e = t + k*256;
      int row = e >> 5, col = e & 31;
      tile[row][col] = p[(size_t)(n0+row)*DD + col];
    }
    __syncthreads();
    #pragma unroll
    for (int r=0;r<8;r++){
      int row = nc*8 + r;
      float val = expf(tile[row][dl] - mm) * inv;
      unsigned short hh = f2bf(val);
      outh[dl][row] = hh;
      outl[dl][row] = f2bf(val - bf2f(hh));
    }
    __syncthreads();
    #pragma unroll
    for (int k=0;k<8;k++){
      int e = t + k*256;
      int dd = e >> 6, nn = e & 63;
      qh[(size_t)dd*NN + n0 + nn] = outh[dd][nn];
      ql[(size_t)dd*NN + n0 + nn] = outl[dd][nn];
    }
    __syncthreads();
  }
}

// ---------------- batched transpose + split: fp32 [z][R][C] -> u16 hi/lo [z][C][R] ---
__global__ __launch_bounds__(256) void tsplit_kernel(const float* __restrict__ in,
    unsigned short* __restrict__ oh, unsigned short* __restrict__ ol, int R, int Cc){
  const size_t zb = (size_t)blockIdx.z * R * Cc;
  const float* ip = in + zb;
  unsigned short* ohp = oh + zb;
  unsigned short* olp = ol + zb;
  __shared__ float tile[32][33];
  const int c0 = blockIdx.x*32, r0 = blockIdx.y*32;
  const int j = threadIdx.x & 31, i4 = threadIdx.x >> 5;
  #pragma unroll
  for (int s=0;s<4;s++){
    int i = i4*4+s;
    tile[i][j] = ip[(size_t)(r0+i)*Cc + c0 + j];
  }
  __syncthreads();
  #pragma unroll
  for (int s=0;s<4;s++){
    int i = i4*4+s;
    float x = tile[j][i];
    unsigned short h = f2bf(x);
    ohp[(size_t)(c0+i)*R + r0 + j] = h;
    olp[(size_t)(c0+i)*R + r0 + j] = f2bf(x - bf2f(h));
  }
}

// ---------------- channel attention (PACKED u32 qkv input, split bf16 output) -----
__global__ __launch_bounds__(256) void chattn_mfma_kernel(
    const unsigned int* __restrict__ qp, const float* __restrict__ temp,
    unsigned short* __restrict__ coh, unsigned short* __restrict__ col)
{
  const int bh = blockIdx.x, b = bh >> 3, h = bh & 7;
  const int t = threadIdx.x, w = t >> 6, lane = t & 63;
  const int lr = lane & 15, g = lane >> 4;

  __shared__ __align__(16) unsigned char ldsA[27648];
  unsigned short (*Qh)[72] = (unsigned short(*)[72])(ldsA);
  unsigned short (*Ql)[72] = (unsigned short(*)[72])(ldsA + 6912);
  unsigned short (*Kh)[72] = (unsigned short(*)[72])(ldsA + 13824);
  unsigned short (*Kl)[72] = (unsigned short(*)[72])(ldsA + 20736);
  unsigned short (*Vh)[72] = (unsigned short(*)[72])(ldsA);
  unsigned short (*Vl)[72] = (unsigned short(*)[72])(ldsA + 9216);
  __shared__ unsigned short Ph[48][72], Pl[48][72];
  __shared__ float S[48][49];
  __shared__ float qn[48], kn[48];

  const size_t base = (size_t)b*NN*1152 + (size_t)h*48;

  int agrp[3], apr[3], aoff[3];
  #pragma unroll
  for (int l=0;l<3;l++){
    int idx = l*256+t;
    int mo = (idx>=384) ? 1 : 0;
    int a = idx - mo*384;
    agrp[l] = a%12; apr[l] = a/12; aoff[l] = mo*384;
  }

  f32x4v acc[12];
  #pragma unroll
  for (int i=0;i<12;i++) acc[i] = (f32x4v){0.f,0.f,0.f,0.f};

  uint4 p0[3], p1[3];
  #pragma unroll
  for (int l=0;l<3;l++){
    const size_t a = base + (size_t)(apr[l]*2)*1152 + aoff[l] + agrp[l]*4;
    p0[l] = *(const uint4*)(qp + a);
    p1[l] = *(const uint4*)(qp + a + 1152);
  }

  for (int nc=0; nc<16; nc++){
    #pragma unroll
    for (int l=0;l<3;l++){
      unsigned short (*Dh)[72] = aoff[l] ? Kh : Qh;
      unsigned short (*Dl)[72] = aoff[l] ? Kl : Ql;
      const unsigned w0[4] = {p0[l].x, p0[l].y, p0[l].z, p0[l].w};
      const unsigned w1[4] = {p1[l].x, p1[l].y, p1[l].z, p1[l].w};
      #pragma unroll
      for (int c=0;c<4;c++){
        int d = agrp[l]*4+c;
        *(unsigned int*)&Dh[d][apr[l]*2] = (w0[c] & 0xffffu) | (w1[c] << 16);
        *(unsigned int*)&Dl[d][apr[l]*2] = (w0[c] >> 16)     | (w1[c] & 0xffff0000u);
      }
    }
    __syncthreads();
    if (nc < 15){
      #pragma unroll
      for (int l=0;l<3;l++){
        const size_t a = base + (size_t)((nc+1)*64 + apr[l]*2)*1152 + aoff[l] + agrp[l]*4;
        p0[l] = *(const uint4*)(qp + a);
        p1[l] = *(const uint4*)(qp + a + 1152);
      }
    }
    if (w < 3){
      #pragma unroll
      for (int ks=0;ks<2;ks++){
        bf16x8 a_h = *(const bf16x8*)&Qh[w*16+lr][ks*32+g*8];
        bf16x8 a_l = *(const bf16x8*)&Ql[w*16+lr][ks*32+g*8];
        #pragma unroll
        for (int c=0;c<3;c++){
          bf16x8 b_h = *(const bf16x8*)&Kh[c*16+lr][ks*32+g*8];
          bf16x8 b_l = *(const bf16x8*)&Kl[c*16+lr][ks*32+g*8];
          acc[c] = __builtin_amdgcn_mfma_f32_16x16x32_bf16(a_h, b_h, acc[c], 0,0,0);
          acc[c] = __builtin_amdgcn_mfma_f32_16x16x32_bf16(a_l, b_h, acc[c], 0,0,0);
          acc[c] = __builtin_amdgcn_mfma_f32_16x16x32_bf16(a_h, b_l, acc[c], 0,0,0);
        }
      }
    } else {
      #pragma unroll
      for (int ks=0;ks<2;ks++){
        #pragma unroll
        for (int c=0;c<3;c++){
          bf16x8 qh_ = *(const bf16x8*)&Qh[c*16+lr][ks*32+g*8];
          bf16x8 ql_ = *(const bf16x8*)&Ql[c*16+lr][ks*32+g*8];
          bf16x8 kh_ = *(const bf16x8*)&Kh[c*16+lr][ks*32+g*8];
          bf16x8 kl_ = *(const bf16x8*)&Kl[c*16+lr][ks*32+g*8];
          acc[c]   = __builtin_amdgcn_mfma_f32_16x16x32_bf16(qh_, qh_, acc[c],   0,0,0);
          acc[3+c] = __builtin_amdgcn_mfma_f32_16x16x32_bf16(qh_, ql_, acc[3+c], 0,0,0);
          acc[6+c] = __builtin_amdgcn_mfma_f32_16x16x32_bf16(kh_, kh_, acc[6+c], 0,0,0);
          acc[9+c] = __builtin_amdgcn_mfma_f32_16x16x32_bf16(kh_, kl_, acc[9+c], 0,0,0);
        }
      }
    }
    __syncthreads();
  }

  const float tp = temp[h];
  if (w == 3){
    if ((lane>>4) == ((lane&15)>>2)){
      int p = lane & 15, r = p & 3;
      #pragma unroll
      for (int c=0;c<3;c++){
        float q2 = fmaxf(acc[c][r]   + 2.f*acc[3+c][r], 0.f);
        float k2 = fmaxf(acc[6+c][r] + 2.f*acc[9+c][r], 0.f);
        qn[c*16+p] = fmaxf(sqrtf(q2), 1e-12f);
        kn[c*16+p] = fmaxf(sqrtf(k2), 1e-12f);
      }
    }
  }
  __syncthreads();
  if (w < 3){
    #pragma unroll
    for (int c=0;c<3;c++){
      #pragma unroll
      for (int r=0;r<4;r++){
        int i = w*16 + g*4 + r, j = c*16 + lr;
        S[i][j] = acc[c][r]*tp/(qn[i]*kn[j]);
      }
    }
  }
  __syncthreads();

  int vgrp[3], vtk[3];
  #pragma unroll
  for (int l=0;l<3;l++){ int idx=l*256+t; vtk[l]=idx/12; vgrp[l]=idx%12; }
  uint4 pv[3];
  #pragma unroll
  for (int l=0;l<3;l++){
    const size_t a = base + (size_t)vtk[l]*1152 + 768 + vgrp[l]*4;
    pv[l] = *(const uint4*)(qp + a);
  }

  if (t < 48){
    float m = -3.0e38f;
    for (int j=0;j<48;j++) m = fmaxf(m, S[t][j]);
    float s = 0.f;
    for (int j=0;j<48;j++){ float e_ = expf(S[t][j]-m); S[t][j] = e_; s += e_; }
    float inv = 1.f/s;
    for (int j=0;j<48;j++){
      float p = S[t][j]*inv;
      unsigned short hp = f2bf(p);
      Ph[t][j] = hp; Pl[t][j] = f2bf(p - bf2f(hp));
    }
    #pragma unroll
    for (int j=48;j<64;j++){ Ph[t][j]=0; Pl[t][j]=0; }
  } else {
    const u16x4 z4 = (u16x4){0,0,0,0};
    for (int idx=t-48; idx<512; idx+=208){
      int tk = idx>>3, q = idx&7;
      if (q<4) *(u16x4*)&Vh[tk][48+(q&3)*4] = z4;
      else     *(u16x4*)&Vl[tk][48+(q&3)*4] = z4;
    }
  }
  __syncthreads();

  bf16x8 pfh[3][2], pfl[3][2];
  #pragma unroll
  for (int it=0;it<3;it++)
    #pragma unroll
    for (int ks=0;ks<2;ks++){
      pfh[it][ks] = *(const bf16x8*)&Ph[it*16+lr][ks*32+g*8];
      pfl[it][ks] = *(const bf16x8*)&Pl[it*16+lr][ks*32+g*8];
    }

  for (int vc=0; vc<16; vc++){
    #pragma unroll
    for (int l=0;l<3;l++){
      const unsigned pw[4] = {pv[l].x, pv[l].y, pv[l].z, pv[l].w};
      u16x4 hv, lv;
      #pragma unroll
      for (int c=0;c<4;c++){
        hv[c] = (unsigned short)(pw[c] & 0xffffu);
        lv[c] = (unsigned short)(pw[c] >> 16);
      }
      *(u16x4*)&Vh[vtk[l]][vgrp[l]*4] = hv;
      *(u16x4*)&Vl[vtk[l]][vgrp[l]*4] = lv;
    }
    __syncthreads();
    if (vc < 15){
      #pragma unroll
      for (int l=0;l<3;l++){
        const size_t a = base + (size_t)((vc+1)*64+vtk[l])*1152 + 768 + vgrp[l]*4;
        pv[l] = *(const uint4*)(qp + a);
      }
    }
    bf16x8 vfh[2], vfl[2];
    #pragma unroll
    for (int ks=0;ks<2;ks++){
      vfh[ks] = *(const bf16x8*)&Vh[w*16+lr][ks*32+g*8];
      vfl[ks] = *(const bf16x8*)&Vl[w*16+lr][ks*32+g*8];
    }
    f32x4v o[3];
    #pragma unroll
    for (int it=0;it<3;it++) o[it] = (f32x4v){0.f,0.f,0.f,0.f};
    #pragma unroll
    for (int it=0;it<3;it++)
      #pragma unroll
      for (int ks=0;ks<2;ks++){
        o[it] = __builtin_amdgcn_mfma_f32_16x16x32_bf16(pfh[it][ks], vfh[ks], o[it], 0,0,0);
        o[it] = __builtin_amdgcn_mfma_f32_16x16x32_bf16(pfl[it][ks], vfh[ks], o[it], 0,0,0);
        o[it] = __builtin_amdgcn_mfma_f32_16x16x32_bf16(pfh[it][ks], vfl[ks], o[it], 0,0,0);
      }
    const int n = vc*64 + w*16 + lr;
    #pragma unroll
    for (int it=0;it<3;it++){
      const size_t off = ((size_t)b*NN + n)*DD + h*48 + it*16 + g*4;
      u16x4 hv, lv;
      #pragma unroll
      for (int r=0;r<4;r++){
        float x = o[it][r];
        unsigned short hh = f2bf(x);
        hv[r] = hh; lv[r] = f2bf(x - bf2f(hh));
      }
      *(u16x4*)(coh + off) = hv;
      *(u16x4*)(col + off) = lv;
    }
    __syncthreads();
  }
}

// ---------------- fused phase-A weight prep: qkv (432 blocks) + proj (144) -------
__global__ __launch_bounds__(256) void wprep2_kernel(
    const float* __restrict__ qkvw, unsigned short* __restrict__ qwh, unsigned short* __restrict__ qwl,
    const float* __restrict__ projw, unsigned short* __restrict__ pwh, unsigned short* __restrict__ pwl)
{
  __shared__ float tile[32][33];
  const int bid = blockIdx.x;
  const float* in; unsigned short *oh, *ol; int Nin, bx, by;
  if (bid < 432){ in = qkvw;  oh = qwh; ol = qwl; Nin = 1152; bx = bid % 36; by = bid / 36; }
  else { int k = bid - 432; in = projw; oh = pwh; ol = pwl; Nin = DD;   bx = k % 12;  by = k / 12; }
  const int n0 = bx*32, k0 = by*32;
  const int j = threadIdx.x & 31, i4 = threadIdx.x >> 5;
  #pragma unroll
  for (int s=0;s<4;s++){
    int i = i4*4+s;
    tile[i][j] = in[(size_t)(k0+i)*Nin + n0 + j];
  }
  __syncthreads();
  #pragma unroll
  for (int s=0;s<4;s++){
    int i = i4*4+s;
    float x = tile[j][i];
    unsigned short h = f2bf(x);
    oh[(size_t)(n0+i)*DD + k0 + j] = h;
    ol[(size_t)(n0+i)*DD + k0 + j] = f2bf(x - bf2f(h));
  }
}

// ---------------- weight prep: transpose [K,Nin] -> bf16 hi/lo (fc1/fc2) ---------
__global__ __launch_bounds__(256) void wconv_t_kernel(const float* __restrict__ in,
    unsigned short* __restrict__ oh, unsigned short* __restrict__ ol, int K, int Nin){
  __shared__ float tile[32][33];
  const int n0 = blockIdx.x*32, k0 = blockIdx.y*32;
  const int j = threadIdx.x & 31, i4 = threadIdx.x >> 5;
  #pragma unroll
  for (int s=0;s<4;s++){
    int i = i4*4+s;
    tile[i][j] = (n0 + j < Nin) ? in[(size_t)(k0+i)*Nin + n0 + j] : 0.f;
  }
  __syncthreads();
  #pragma unroll
  for (int s=0;s<4;s++){
    int i = i4*4+s;
    float x = tile[j][i];
    unsigned short h = f2bf(x);
    oh[(size_t)(n0+i)*K + k0 + j] = h;
    ol[(size_t)(n0+i)*K + k0 + j] = f2bf(x - bf2f(h));
  }
}

// ---------------- elementwise split fp32 -> bf16 hi/lo ----------------
__global__ __launch_bounds__(256) void wconv_kernel(const float* __restrict__ in,
    unsigned short* __restrict__ oh, unsigned short* __restrict__ ol, int n){
  int i = blockIdx.x*256 + threadIdx.x;
  if (i < n){
    float x = in[i];
    unsigned short h = f2bf(x);
    oh[i] = h;
    ol[i] = f2bf(x - bf2f(h));
  }
}

// ---------------- bf16x3 MFMA GEMM 128x128: dbuf LDS + distance-2 prefetch --------
// Verified structure (R6..R12): 2 blocks/CU, 0 bank conflicts, ~830-860 TF eff.
template<bool BIAS_, bool RES_, bool SPLIT_, bool PACK32_>
__global__ __launch_bounds__(256) void gemm_bf16x3s_kernel(
    const unsigned short* __restrict__ Ah, const unsigned short* __restrict__ Al,
    const unsigned short* __restrict__ Bh, const unsigned short* __restrict__ Bl,
    const float* __restrict__ bias, const float* __restrict__ res,
    const float* __restrict__ res2, int Mh2,
    float* __restrict__ C, unsigned short* __restrict__ Ch, unsigned short* __restrict__ Cl,
    int M, int N, int K, size_t sAz, size_t sBz, size_t sCz)
{
  const int t = threadIdx.x;
  const int nwg = gridDim.x*gridDim.y;
  const int lin = blockIdx.y*gridDim.x + blockIdx.x;
  const int swz = ((nwg & 7)==0) ? ((lin & 7)*(nwg >> 3) + (lin >> 3)) : lin;
  const int bx = swz % gridDim.x, by = swz / gridDim.x;
  const int m0 = by*128, n0 = bx*128;
  const size_t zo = (size_t)blockIdx.z;

  __shared__ unsigned short As_h0[128][32], As_l0[128][32];
  __shared__ unsigned short Bs_h0[128][32], Bs_l0[128][32];
  __shared__ unsigned short As_h1[128][32], As_l1[128][32];
  __shared__ unsigned short Bs_h1[128][32], Bs_l1[128][32];

  const unsigned short* Ahb = Ah + zo*sAz + (size_t)m0*K;
  const unsigned short* Alb = Al + zo*sAz + (size_t)m0*K;
  const unsigned short* Bhb = Bh + zo*sBz + (size_t)n0*K;
  const unsigned short* Blb = Bl + zo*sBz + (size_t)n0*K;

  f32x4v acc[4][4];
  #pragma unroll
  for (int i=0;i<4;i++)
    #pragma unroll
    for (int j=0;j<4;j++) acc[i][j] = (f32x4v){0.f,0.f,0.f,0.f};

  const int w  = t >> 6;
  const int wm = w >> 1, wn = w & 1;
  const int lr = t & 15, g = (t & 63) >> 4;
  const int srow = t >> 1;
  const int kb0  = (t & 1)*2;
  const int ssw  = (srow >> 1) & 3;
  const int ks0  = ((kb0+0) ^ ssw)*8;
  const int ks1  = ((kb0+1) ^ ssw)*8;

  uint4 aAh0,aAh1,aAl0,aAl1,aBh0,aBh1,aBl0,aBl1;
  uint4 bAh0,bAh1,bAl0,bAl1,bBh0,bBh1,bBl0,bBl1;

#define LOADT(P, K0) { \
    const size_t go0 = (size_t)srow*K + (size_t)(K0) + (size_t)(kb0*8); \
    P##Ah0 = *(const uint4*)(Ahb + go0); P##Ah1 = *(const uint4*)(Ahb + go0 + 8); \
    P##Al0 = *(const uint4*)(Alb + go0); P##Al1 = *(const uint4*)(Alb + go0 + 8); \
    P##Bh0 = *(const uint4*)(Bhb + go0); P##Bh1 = *(const uint4*)(Bhb + go0 + 8); \
    P##Bl0 = *(const uint4*)(Blb + go0); P##Bl1 = *(const uint4*)(Blb + go0 + 8); }

#define WRITET(BUF, P) { \
    *(uint4*)&As_h##BUF[srow][ks0] = P##Ah0; *(uint4*)&As_h##BUF[srow][ks1] = P##Ah1; \
    *(uint4*)&As_l##BUF[srow][ks0] = P##Al0; *(uint4*)&As_l##BUF[srow][ks1] = P##Al1; \
    *(uint4*)&Bs_h##BUF[srow][ks0] = P##Bh0; *(uint4*)&Bs_h##BUF[srow][ks1] = P##Bh1; \
    *(uint4*)&Bs_l##BUF[srow][ks0] = P##Bl0; *(uint4*)&Bs_l##BUF[srow][ks1] = P##Bl1; }

#define COMPUTET(BUF) { \
    bf16x8 ah[4], al[4], bhf[4], blf[4]; \
    _Pragma("unroll") \
    for (int i=0;i<4;i++){ \
      const int ra = wm*64 + i*16 + lr; \
      const int ka = (g ^ ((ra>>1)&3))*8; \
      ah[i]  = *(const bf16x8*)&As_h##BUF[ra][ka]; \
      al[i]  = *(const bf16x8*)&As_l##BUF[ra][ka]; \
      const int rb = wn*64 + i*16 + lr; \
      const int kb = (g ^ ((rb>>1)&3))*8; \
      bhf[i] = *(const bf16x8*)&Bs_h##BUF[rb][kb]; \
      blf[i] = *(const bf16x8*)&Bs_l##BUF[rb][kb]; \
    } \
    _Pragma("unroll") \
    for (int mi=0;mi<4;mi++) \
      _Pragma("unroll") \
      for (int ni=0;ni<4;ni++){ \
        f32x4v c_ = acc[mi][ni]; \
        c_ = __builtin_amdgcn_mfma_f32_16x16x32_bf16(ah[mi], bhf[ni], c_, 0,0,0); \
        c_ = __builtin_amdgcn_mfma_f32_16x16x32_bf16(al[mi], bhf[ni], c_, 0,0,0); \
        c_ = __builtin_amdgcn_mfma_f32_16x16x32_bf16(ah[mi], blf[ni], c_, 0,0,0); \
        acc[mi][ni] = c_; \
      } }

  const int nk = K >> 5;
  LOADT(a, 0);
  WRITET(0, a);
  LOADT(a, 32);
  __syncthreads();

  for (int kt = 0; kt < nk; kt += 2){
    if (kt+2 < nk) LOADT(b, (kt+2)*32);
    COMPUTET(0);
    WRITET(1, a);
    __syncthreads();
    if (kt+3 < nk) LOADT(a, (kt+3)*32);
    COMPUTET(1);
    if (kt+2 < nk){ WRITET(0, b); }
    __syncthreads();
  }

#undef LOADT
#undef WRITET
#undef COMPUTET

  if (PACK32_){
    unsigned int* Cp = (unsigned int*)Ch + zo*sCz;
    #pragma unroll
    for (int ni=0;ni<4;ni++){
      const int col = n0 + wn*64 + ni*16 + lr;
      #pragma unroll
      for (int mi=0;mi<4;mi++){
        const int r0 = m0 + wm*64 + mi*16 + g*4;
        #pragma unroll
        for (int r=0;r<4;r++){
          float v = acc[mi][ni][r];
          unsigned short hv = f2bf(v);
          unsigned short lv = f2bf(v - bf2f(hv));
          Cp[(size_t)(r0+r)*N + col] = (unsigned)hv | ((unsigned)lv << 16);
        }
      }
    }
  } else if (SPLIT_){
    unsigned short* Chb = Ch + zo*sCz;
    unsigned short* Clb = Cl + zo*sCz;
    #pragma unroll
    for (int ni=0;ni<4;ni++){
      const int col = n0 + wn*64 + ni*16 + lr;
      #pragma unroll
      for (int mi=0;mi<4;mi++){
        const int r0 = m0 + wm*64 + mi*16 + g*4;
        #pragma unroll
        for (int r=0;r<4;r++){
          float v = acc[mi][ni][r];
          unsigned short hv = f2bf(v);
          const size_t off = (size_t)(r0+r)*N + col;
          Chb[off] = hv;
          Clb[off] = f2bf(v - bf2f(hv));
        }
      }
    }
  } else {
    float* Cb = C + zo*sCz;
    const float* resb = nullptr;
    size_t roff = 0;
    if (RES_){
      if (res2 != nullptr && m0 >= Mh2){ resb = res2; roff = (size_t)Mh2; }
      else resb = res + zo*sCz;
    }
    #pragma unroll
    for (int ni=0;ni<4;ni++){
      const int col = n0 + wn*64 + ni*16 + lr;
      const float bb = BIAS_ ? bias[col] : 0.f;
      #pragma unroll
      for (int mi=0;mi<4;mi++){
        const int r0 = m0 + wm*64 + mi*16 + g*4;
        #pragma unroll
        for (int r=0;r<4;r++){
          float v = acc[mi][ni][r] + bb;
          if (RES_) v += resb[((size_t)(r0+r) - roff)*N + col];
          Cb[(size_t)(r0+r)*N + col] = v;
        }
      }
    }
  }
}

// ---------------- LN(rep)+concat -> tx, fused LN2 -> split y2 ----------------
__global__ __launch_bounds__(256) void ln_concat_ln2_kernel(const float* __restrict__ rep,
    const float* __restrict__ g1, const float* __restrict__ b1,
    const float* __restrict__ ch1, const float* __restrict__ ch2,
    const float* __restrict__ g2, const float* __restrict__ b2,
    float* __restrict__ tx, unsigned short* __restrict__ y2h, unsigned short* __restrict__ y2l){
  const int row = blockIdx.x;
  const float* x = rep + (size_t)row*D2;
  float xv[3];
  float s=0.f;
  #pragma unroll
  for (int q=0;q<3;q++){ xv[q] = x[threadIdx.x + q*256]; s += xv[q]; }
  s = blockReduceSum256(s);
  const float mu = s / (float)D2;
  float v=0.f;
  #pragma unroll
  for (int q=0;q<3;q++){ float d = xv[q]-mu; v += d*d; }
  v = blockReduceSum256(v);
  const float rs = rsqrtf(v/(float)D2 + 1e-5f);
  float tv[3];
  #pragma unroll
  for (int q=0;q<3;q++){
    int i = threadIdx.x + q*256;
    float val = (xv[q]-mu)*rs*g1[i] + b1[i];
    float rv = (i<DD) ? ch1[(size_t)row*DD + i] : ch2[(size_t)row*DD + i - DD];
    tv[q] = val + rv;
    tx[(size_t)row*D2 + i] = tv[q];
  }
  float s2 = tv[0]+tv[1]+tv[2];
  s2 = blockReduceSum256(s2);
  const float mu2 = s2 / (float)D2;
  float v2=0.f;
  #pragma unroll
  for (int q=0;q<3;q++){ float d = tv[q]-mu2; v2 += d*d; }
  v2 = blockReduceSum256(v2);
  const float rs2 = rsqrtf(v2/(float)D2 + 1e-5f);
  #pragma unroll
  for (int q=0;q<3;q++){
    int i = threadIdx.x + q*256;
    float y = (tv[q]-mu2)*rs2*g2[i] + b2[i];
    unsigned short hh = f2bf(y);
    y2h[(size_t)row*D2 + i] = hh;
    y2l[(size_t)row*D2 + i] = f2bf(y - bf2f(hh));
  }
}

// ---------------- depthwise 3x3 conv + bias + exact GELU (split bf16 out) --------
__global__ __launch_bounds__(256) void dwconv_gelu_kernel(const float* __restrict__ h1,
    const float* __restrict__ w, const float* __restrict__ bias,
    unsigned short* __restrict__ gh, unsigned short* __restrict__ gl){
  const int idx = blockIdx.x*256 + threadIdx.x;
  const int b   = idx / 12288;
  const int r   = idx - b*12288;
  const int hh  = r / 384;
  const int c4  = r - hh*384;
  const int c   = c4*4;
  const float* base = h1 + (size_t)b*NN*C2 + c;
  const size_t obase = ((size_t)b*NN + hh*32)*C2 + c;

  f32x4v wk[9];
  #pragma unroll
  for (int k=0;k<9;k++){
    f32x4v t_;
    #pragma unroll
    for (int q=0;q<4;q++) t_[q] = w[(size_t)(c+q)*9 + k];
    wk[k] = t_;
  }
  f32x4v bvv;
  {
    const float4 bb = *(const float4*)(bias + c);
    bvv = (f32x4v){bb.x, bb.y, bb.z, bb.w};
  }

  const bool hm = (hh > 0), hp = (hh < 31);
  const f32x4v z4 = (f32x4v){0.f,0.f,0.f,0.f};
  const size_t rm = (size_t)((hh-1)*32)*C2;
  const size_t r0 = (size_t)( hh   *32)*C2;
  const size_t rp = (size_t)((hh+1)*32)*C2;

  f32x4v A0,A1,A2, B0,B1,B2, C0,C1,C2c;
  A0=z4; A1=z4; A2=z4;
  B0 = hm ? *(const f32x4v*)(base + rm) : z4;
  B1 =      *(const f32x4v*)(base + r0);
  B2 = hp ? *(const f32x4v*)(base + rp) : z4;
  C0 = hm ? *(const f32x4v*)(base + rm + C2) : z4;
  C1 =      *(const f32x4v*)(base + r0 + C2);
  C2c= hp ? *(const f32x4v*)(base + rp + C2) : z4;

  for (int ww=0; ww<32; ww++){
    f32x4v N0,N1,N2;
    if (ww < 30){
      const size_t co_ = (size_t)(ww+2)*C2;
      N0 = hm ? *(const f32x4v*)(base + rm + co_) : z4;
      N1 =      *(const f32x4v*)(base + r0 + co_) ;
      N2 = hp ? *(const f32x4v*)(base + rp + co_) : z4;
    } else { N0=z4; N1=z4; N2=z4; }

    f32x4v s = bvv;
    s += wk[0]*A0 + wk[1]*B0 + wk[2]*C0;
    s += wk[3]*A1 + wk[4]*B1 + wk[5]*C1;
    s += wk[6]*A2 + wk[7]*B2 + wk[8]*C2c;

    u16x4 hv, lv;
    #pragma unroll
    for (int q=0;q<4;q++){
      float rlt = 0.5f*s[q]*(1.f + erff(s[q]*0.70710678118654752f));
      unsigned short hhv = f2bf(rlt);
      hv[q] = hhv; lv[q] = f2bf(rlt - bf2f(hhv));
    }
    *(u16x4*)(gh + obase + (size_t)ww*C2) = hv;
    *(u16x4*)(gl + obase + (size_t)ww*C2) = lv;

    A0=B0; A1=B1; A2=B2;
    B0=C0; B1=C1; B2=C2c;
    C0=N0; C1=N1; C2c=N2;
  }
}

// ---------------- launch ----------------
extern "C" void kernel_launch(void* const* d_in, const int* in_sizes, int n_in,
                              void* d_out, int out_size, void* d_ws, size_t ws_size,
                              hipStream_t stream) {
  const float* x1     = (const float*)d_in[0];
  const float* x2     = (const float*)d_in[1];
  const float* ln1_g  = (const float*)d_in[2];
  const float* ln1_b  = (const float*)d_in[3];
  const float* qkv_w  = (const float*)d_in[4];
  const float* ca_temp= (const float*)d_in[5];
  const float* proj_w = (const float*)d_in[6];
  const float* proj_b = (const float*)d_in[7];
  const float* ln3_g  = (const float*)d_in[8];
  const float* ln3_b  = (const float*)d_in[9];
  const float* rp_w   = (const float*)d_in[10];
  const float* rp_b   = (const float*)d_in[11];
  const float* cn_g   = (const float*)d_in[12];
  const float* cn_b   = (const float*)d_in[13];
  const float* ln2_g  = (const float*)d_in[14];
  const float* ln2_b  = (const float*)d_in[15];
  const float* fc1_w  = (const float*)d_in[16];
  const float* fc1_b  = (const float*)d_in[17];
  const float* dw_w   = (const float*)d_in[18];
  const float* dw_b   = (const float*)d_in[19];
  const float* fc2_w  = (const float*)d_in[20];
  const float* fc2_b  = (const float*)d_in[21];
  float* out = (float*)d_out;
  float* W   = (float*)d_ws;

  // ---- workspace plan (identical to R11/R12) ----
  unsigned short* ycoh = (unsigned short*)out;
  unsigned short* ycol = ycoh + 12582912u;
  unsigned short* coh  = ycoh;
  unsigned short* col  = ycol;
  unsigned int*   qkvp = (unsigned int*)W;                 // 32768*1152 u32
  unsigned short* qkvwT_h  = (unsigned short*)(W + 37748736ull);
  unsigned short* qkvwT_l  = qkvwT_h + 442368u;
  unsigned short* projwT_h = qkvwT_l + 442368u;
  unsigned short* projwT_l = projwT_h + 147456u;
  float* ch12 = W;
  float* n12  = W + 12582912ull;
  unsigned short* QSh = (unsigned short*)(W + 25165824ull);
  unsigned short* QSl = QSh + 6291456u;
  unsigned short* KSt_h = (unsigned short*)(W + 31457280ull);
  unsigned short* KSt_l = KSt_h + 6291456u;
  unsigned short* rpw_h = (unsigned short*)(W + 37748736ull);
  unsigned short* rpw_l = rpw_h + 294912u;
  unsigned short* n1t_h = (unsigned short*)(W + 38043648ull);
  unsigned short* n1t_l = n1t_h + 6291456u;
  unsigned short* ctxT_h = (unsigned short*)(W + 12582912ull);
  unsigned short* ctxT_l = ctxT_h + 2359296u;
  unsigned short* ATbh = (unsigned short*)(W + 14942208ull);
  unsigned short* ATbl = ATbh + 6291456u;
  float* rep = W + 25165824ull;
  float* txp = out;
  unsigned short* y2h = (unsigned short*)(W + 37748736ull);
  unsigned short* y2l = y2h + 12582912u;
  float* h1 = W;
  unsigned short* fc1wT_h = (unsigned short*)(W + 25165824ull);
  unsigned short* fc1wT_l = fc1wT_h + 1179648u;
  unsigned short* gh = (unsigned short*)(W + 25165824ull);
  unsigned short* gl = (unsigned short*)(W + 37748736ull);
  unsigned short* fc2wT_h = (unsigned short*)W;
  unsigned short* fc2wT_l = fc2wT_h + 1179648u;

  // ---- phase-A weight prep (qkv + proj fused, 576 blocks) ----
  wprep2_kernel<<<dim3(576), dim3(256), 0, stream>>>(
      qkv_w, qkvwT_h, qkvwT_l, proj_w, projwT_h, projwT_l);

  // ---- channel attention, merged streams (batch 32) ----
  ln_split2_kernel<<<dim3(M2), dim3(256), 0, stream>>>(x1, x2, MH, ln1_g, ln1_b, ycoh, ycol, DD);
  gemm_bf16x3s_kernel<false,false,false,true><<<dim3(1152/128, M2/128), dim3(256), 0, stream>>>(
      ycoh, ycol, qkvwT_h, qkvwT_l, nullptr, nullptr, nullptr, 0,
      nullptr, (unsigned short*)qkvp, nullptr, M2, 1152, DD, 0,0,0);
  chattn_mfma_kernel<<<dim3(32*NHEAD), dim3(256), 0, stream>>>(qkvp, ca_temp, coh, col);
  gemm_bf16x3s_kernel<true,true,false,false><<<dim3(DD/128, M2/128), dim3(256), 0, stream>>>(
      coh, col, projwT_h, projwT_l, proj_b, x1, x2, MH,
      ch12, nullptr, nullptr, M2, DD, DD, 0,0,0);

  // ---- cross attention ----
  wconv_kernel<<<dim3(294912/256), dim3(256), 0, stream>>>(rp_w, rpw_h, rpw_l, 294912);
  ln_kernel<<<dim3(M2), dim3(256), 0, stream>>>(ch12, ln3_g, ln3_b, n12, DD);
  const float* n2half = n12 + (size_t)MH*DD;
  rowsoftmax_split_kernel<<<dim3(MH), dim3(256), 0, stream>>>(n2half, QSh, QSl, DD);
  colsoftmax_tsplit_kernel<<<dim3(DD/32, BN), dim3(256), 0, stream>>>(n2half, KSt_h, KSt_l);
  tsplit_kernel<<<dim3(DD/32, NN/32, BN), dim3(256), 0, stream>>>(n12, n1t_h, n1t_l, NN, DD);
  // ctxT[b][d][e] = sum_n n1[n][d]*KS[n][e]
  gemm_bf16x3s_kernel<false,false,true,false><<<dim3(DD/128, DD/128, BN), dim3(256), 0, stream>>>(
      n1t_h, n1t_l, KSt_h, KSt_l, nullptr, nullptr, nullptr, 0,
      nullptr, ctxT_h, ctxT_l, DD, DD, NN, (size_t)DD*NN, (size_t)DD*NN, (size_t)DD*DD);
  // ATb[b][n][d] = sum_e QS[n][e]*ctxT[d][e]
  gemm_bf16x3s_kernel<false,false,true,false><<<dim3(DD/128, NN/128, BN), dim3(256), 0, stream>>>(
      QSh, QSl, ctxT_h, ctxT_l, nullptr, nullptr, nullptr, 0,
      nullptr, ATbh, ATbl, NN, DD, DD, (size_t)NN*DD, (size_t)DD*DD, (size_t)NN*DD);
  // rep = ATb [MH,D] * rp_w^T + rp_b
  gemm_bf16x3s_kernel<true,false,false,false><<<dim3(D2/128, MH/128), dim3(256), 0, stream>>>(
      ATbh, ATbl, rpw_h, rpw_l, rp_b, nullptr, nullptr, 0,
      rep, nullptr, nullptr, MH, D2, DD, 0,0,0);
  // tx = concat(ch1,ch2) + LN(rep); fused LN2 -> split y2
  ln_concat_ln2_kernel<<<dim3(MH), dim3(256), 0, stream>>>(
      rep, cn_g, cn_b, ch12, ch12 + (size_t)MH*DD, ln2_g, ln2_b, txp, y2h, y2l);

  // ---- mix FFN ----
  wconv_t_kernel<<<dim3(C2/32, D2/32), dim3(256), 0, stream>>>(fc1_w, fc1wT_h, fc1wT_l, D2, C2);
  gemm_bf16x3s_kernel<true,false,false,false><<<dim3(C2/128, MH/128), dim3(256), 0, stream>>>(
      y2h, y2l, fc1wT_h, fc1wT_l, fc1_b, nullptr, nullptr, 0,
      h1, nullptr, nullptr, MH, C2, D2, 0,0,0);
  dwconv_gelu_kernel<<<dim3(196608/256), dim3(256), 0, stream>>>(h1, dw_w, dw_b, gh, gl);
  wconv_t_kernel<<<dim3(D2/32, C2/32), dim3(256), 0, stream>>>(fc2_w, fc2wT_h, fc2wT_l, C2, D2);
  gemm_bf16x3s_kernel<true,true,false,false><<<dim3(D2/128, MH/128), dim3(256), 0, stream>>>(
      gh, gl, fc2wT_h, fc2wT_l, fc2_b, txp, nullptr, 0,
      out, nullptr, nullptr, MH, D2, C2, 0,0,0);
}